// Round 2
// baseline (169.764 us; speedup 1.0000x reference)
//
#include <hip/hip_runtime.h>
#include <stdint.h>

typedef __attribute__((ext_vector_type(8))) short short8;
typedef __attribute__((ext_vector_type(4))) short short4v;
typedef __attribute__((ext_vector_type(4))) float f32x4;

__device__ __forceinline__ short f2bf(float x) {
  union { float f; uint32_t u; } c; c.f = x;
  uint32_t r = (c.u + 0x7FFFu + ((c.u >> 16) & 1u)) >> 16;
  return (short)r;
}
__device__ __forceinline__ float b2f(short s) {
  union { uint32_t u; float f; } c; c.u = ((uint32_t)(uint16_t)s) << 16;
  return c.f;
}

// ---------------- fp32 -> bf16 convert (vectorized) ----------------
__global__ __launch_bounds__(256) void cvt_kernel(const float* __restrict__ in,
                                                  short* __restrict__ out, int n4) {
  int i = blockIdx.x * 256 + threadIdx.x;
  const int stride = gridDim.x * 256;
  for (; i < n4; i += stride) {
    float4 v = reinterpret_cast<const float4*>(in)[i];
    short4v o;
    o.x = f2bf(v.x); o.y = f2bf(v.y); o.z = f2bf(v.z); o.w = f2bf(v.w);
    reinterpret_cast<short4v*>(out)[i] = o;
  }
}

// ------------- fp32 [K][N] -> bf16 [N][K] transpose-convert -------------
__global__ __launch_bounds__(256) void tcvt_kernel(const float* __restrict__ in,
                                                   short* __restrict__ out, int K, int N) {
  __shared__ __align__(16) short tile[32][33];
  const int nb = blockIdx.x * 32, kb = blockIdx.y * 32;
  const int tx = threadIdx.x & 31, ty = threadIdx.x >> 5; // 32 x 8
#pragma unroll
  for (int i = 0; i < 32; i += 8)
    tile[ty + i][tx] = f2bf(in[(size_t)(kb + ty + i) * N + nb + tx]);
  __syncthreads();
#pragma unroll
  for (int i = 0; i < 32; i += 8)
    out[(size_t)(nb + ty + i) * K + kb + tx] = tile[tx][ty + i];
}

// ------------- bf16 V-region transpose: qkv[b][kv][2048+c] -> vT[b][c][kv] -------------
__global__ __launch_bounds__(256) void vtrans_kernel(const short* __restrict__ qkvb,
                                                     short* __restrict__ vT) {
  __shared__ __align__(16) short tile[64][65];
  const int b = blockIdx.z;
  const int kv0 = blockIdx.x * 64, c0 = blockIdx.y * 64;
  const int tx = threadIdx.x & 15, ty = threadIdx.x >> 4; // 16 x 16
  const short* src = qkvb + (size_t)(b * 1024) * 3072 + 2048;
#pragma unroll
  for (int i = 0; i < 64; i += 16) {
    int r = ty + i;
#pragma unroll
    for (int j = 0; j < 4; ++j)
      tile[r][tx * 4 + j] = src[(size_t)(kv0 + r) * 3072 + c0 + tx * 4 + j];
  }
  __syncthreads();
  short* dst = vT + (size_t)b * 1024 * 1024;
#pragma unroll
  for (int i = 0; i < 64; i += 16) {
    int cc = ty + i;
#pragma unroll
    for (int j = 0; j < 4; ++j)
      dst[(size_t)(c0 + cc) * 1024 + kv0 + tx * 4 + j] = tile[tx * 4 + j][cc];
  }
}

// ------------- k-projection precompute: kproj[bh][t] = dot(K[b,t,h,0:3], dir_h) -------------
__global__ __launch_bounds__(256) void kproj_kernel(const short* __restrict__ qkvb,
                                                    const float* __restrict__ hdirs,
                                                    float* __restrict__ kproj) {
  const int i = blockIdx.x * 256 + threadIdx.x; // over 32*1024
  const int bh = i >> 10, tt = i & 1023;
  const int b = bh >> 3, h = bh & 7;
  const float d0 = hdirs[h * 3], d1 = hdirs[h * 3 + 1], d2 = hdirs[h * 3 + 2];
  const short* kr = qkvb + (size_t)(b * 1024 + tt) * 3072 + 1024 + h * 128;
  kproj[i] = b2f(kr[0]) * d0 + b2f(kr[1]) * d1 + b2f(kr[2]) * d2;
}

// ---------------- bf16 MFMA GEMM: C[M][N] = A[M][K] * Bt[N][K]^T ----------------
// 128x128 tile, BK=32, 256 threads (4 waves, 2x2), global_load_lds staging with
// XOR chunk swizzle (chunk c' = c ^ ((r>>1)&3)) applied on the GLOBAL side.
template <int OUT_BF16>
__global__ __launch_bounds__(256) void gemm_kernel(const short* __restrict__ A,
                                                   const short* __restrict__ Bt,
                                                   void* __restrict__ Cout,
                                                   int K, int ldc) {
  __shared__ __align__(16) short Al[2][128 * 32];
  __shared__ __align__(16) short Bl[2][128 * 32];
  const int t = threadIdx.x;
  const int lane = t & 63, w = t >> 6;
  const int wr = w >> 1, wc = w & 1;
  const int g = lane >> 4, c16 = lane & 15;
  const int row0 = blockIdx.y * 128, col0 = blockIdx.x * 128;

  f32x4 acc[4][4];
#pragma unroll
  for (int m = 0; m < 4; ++m)
#pragma unroll
    for (int n = 0; n < 4; ++n) {
      f32x4 z = {0.0f, 0.0f, 0.0f, 0.0f};
      acc[m][n] = z;
    }

  auto stage = [&](int buf, int kt) {
    const int k0 = kt * 32;
#pragma unroll
    for (int i = 0; i < 2; ++i) {
      const int qb = i * 256 + (t & 192); // wave-uniform chunk base
      const int q = qb + lane;
      const int r = q >> 2;
      const int c = (q & 3) ^ ((r >> 1) & 3);
      const short* ga = A + (size_t)(row0 + r) * K + k0 + c * 8;
      const short* gb = Bt + (size_t)(col0 + r) * K + k0 + c * 8;
      __builtin_amdgcn_global_load_lds((const __attribute__((address_space(1))) void*)ga,
                                       (__attribute__((address_space(3))) void*)&Al[buf][qb * 8],
                                       16, 0, 0);
      __builtin_amdgcn_global_load_lds((const __attribute__((address_space(1))) void*)gb,
                                       (__attribute__((address_space(3))) void*)&Bl[buf][qb * 8],
                                       16, 0, 0);
    }
  };

  stage(0, 0);
  __syncthreads();
  const int NK = K >> 5;
  int cur = 0;
  const int rA0 = wr * 64 + c16;
  const int rB0 = wc * 64 + c16;
  for (int kt = 0; kt < NK; ++kt) {
    if (kt + 1 < NK) stage(cur ^ 1, kt + 1);
    short8 aF[4], bF[4];
#pragma unroll
    for (int m = 0; m < 4; ++m) {
      const int r = rA0 + m * 16;
      const int c = g ^ ((r >> 1) & 3);
      aF[m] = *reinterpret_cast<const short8*>(&Al[cur][r * 32 + c * 8]);
    }
#pragma unroll
    for (int n = 0; n < 4; ++n) {
      const int r = rB0 + n * 16;
      const int c = g ^ ((r >> 1) & 3);
      bF[n] = *reinterpret_cast<const short8*>(&Bl[cur][r * 32 + c * 8]);
    }
#pragma unroll
    for (int m = 0; m < 4; ++m)
#pragma unroll
      for (int n = 0; n < 4; ++n)
        acc[m][n] = __builtin_amdgcn_mfma_f32_16x16x32_bf16(aF[m], bF[n], acc[m][n], 0, 0, 0);
    __syncthreads();
    cur ^= 1;
  }

  const int er = row0 + wr * 64 + g * 4;
  const int ec = col0 + wc * 64 + c16;
#pragma unroll
  for (int m = 0; m < 4; ++m)
#pragma unroll
    for (int n = 0; n < 4; ++n)
#pragma unroll
      for (int j = 0; j < 4; ++j) {
        const size_t off = (size_t)(er + m * 16 + j) * ldc + ec + n * 16;
        if (OUT_BF16)
          ((short*)Cout)[off] = f2bf(acc[m][n][j]);
        else
          ((float*)Cout)[off] = acc[m][n][j];
      }
}

// ---------------- fused causal attention with trigram geo bias ----------------
// Barrier-free: 512 blocks x 4 independent waves; each wave owns 16 q rows and
// reads K / V^T fragments directly from global (L2-resident per XCD via swizzle).
__global__ __launch_bounds__(256) void attn_kernel(const short* __restrict__ qkvb,
                                                   const short* __restrict__ vT,
                                                   const float* __restrict__ head_scales,
                                                   const float* __restrict__ hdirs,
                                                   const float* __restrict__ kproj,
                                                   short* __restrict__ attnb) {
  __shared__ __align__(16) short P_lds[4][16 * 64]; // per-wave private

  // XCD-aware swizzle: XCD x serves bh in {4x..4x+3} -> K/V working set 2MB/XCD (L2-fits)
  const int bid = blockIdx.x;          // 0..511
  const int x = bid & 7, r = bid >> 3; // xcd, index-within
  const int bh = x * 4 + (r & 3);
  const int qt = r >> 2;
  const int b = bh >> 3, h = bh & 7;
  const int t = threadIdx.x, lane = t & 63, w = t >> 6;
  const int g = lane >> 4, c16 = lane & 15;
  const int q0w = qt * 64 + w * 16; // this wave's 16 q rows

  const short* qbase = qkvb + (size_t)(b * 1024) * 3072 + h * 128;
  const short* kbase = qbase + 1024;
  const short* vtb = vT + (size_t)bh * 128 * 1024;
  const float* kp = kproj + bh * 1024;

  // Q fragments (A-operand): row = c16, k-chunks g*8 within 32-blocks
  short8 aQ[4];
  {
    const short* qr = qbase + (size_t)(q0w + c16) * 3072 + g * 8;
#pragma unroll
    for (int kk = 0; kk < 4; ++kk) aQ[kk] = *reinterpret_cast<const short8*>(qr + kk * 32);
  }
  const float hs = head_scales[h];
  const float d0 = hdirs[h * 3], d1 = hdirs[h * 3 + 1], d2 = hdirs[h * 3 + 2];
  float hqp[4];
#pragma unroll
  for (int j = 0; j < 4; ++j) {
    const short* qr = qbase + (size_t)(q0w + g * 4 + j) * 3072;
    hqp[j] = hs * (b2f(qr[0]) * d0 + b2f(qr[1]) * d1 + b2f(qr[2]) * d2);
  }

  float m_r[4], l_r[4];
  f32x4 accO[8];
#pragma unroll
  for (int j = 0; j < 4; ++j) { m_r[j] = -1e30f; l_r[j] = 0.0f; }
#pragma unroll
  for (int d = 0; d < 8; ++d) {
    f32x4 z = {0.0f, 0.0f, 0.0f, 0.0f};
    accO[d] = z;
  }

  const float scale = 0.08838834764831845f; // 1/sqrt(128)
  const int nkv = qt + 1;
  short* Pw = P_lds[w];

  for (int kvt = 0; kvt < nkv; ++kvt) {
    const int kv0 = kvt * 64;

    // ---- QK^T + scale + geo bias + causal mask (K frags straight from L2) ----
    float sc[4][4];
#pragma unroll
    for (int n = 0; n < 4; ++n) {
      f32x4 s4 = {0.0f, 0.0f, 0.0f, 0.0f};
      const short* krow = kbase + (size_t)(kv0 + n * 16 + c16) * 3072 + g * 8;
#pragma unroll
      for (int kk = 0; kk < 4; ++kk) {
        short8 bK = *reinterpret_cast<const short8*>(krow + kk * 32);
        s4 = __builtin_amdgcn_mfma_f32_16x16x32_bf16(aQ[kk], bK, s4, 0, 0, 0);
      }
      const float kpv = kp[kv0 + n * 16 + c16];
      const int ka = kv0 + n * 16 + c16;
#pragma unroll
      for (int j = 0; j < 4; ++j) {
        const int qa = q0w + g * 4 + j;
        const float v = s4[j] * scale + hqp[j] * kpv;
        sc[n][j] = (ka <= qa) ? v : -1e30f;
      }
    }

    // ---- online softmax (row reduce across 16 lanes of the group) ----
    float mx[4];
#pragma unroll
    for (int j = 0; j < 4; ++j) {
      float v = fmaxf(fmaxf(sc[0][j], sc[1][j]), fmaxf(sc[2][j], sc[3][j]));
#pragma unroll
      for (int off = 8; off > 0; off >>= 1) v = fmaxf(v, __shfl_xor(v, off, 16));
      mx[j] = v;
    }
    float alpha[4], psum[4];
#pragma unroll
    for (int j = 0; j < 4; ++j) {
      const float mn = fmaxf(m_r[j], mx[j]);
      alpha[j] = __expf(m_r[j] - mn);
      m_r[j] = mn;
      float ps = 0.0f;
#pragma unroll
      for (int n = 0; n < 4; ++n) {
        const float p = __expf(sc[n][j] - mn);
        sc[n][j] = p;
        ps += p;
      }
      psum[j] = ps;
    }
#pragma unroll
    for (int j = 0; j < 4; ++j) {
      float ps = psum[j];
#pragma unroll
      for (int off = 8; off > 0; off >>= 1) ps += __shfl_xor(ps, off, 16);
      l_r[j] = l_r[j] * alpha[j] + ps;
    }
#pragma unroll
    for (int d = 0; d < 8; ++d)
#pragma unroll
      for (int j = 0; j < 4; ++j) accO[d][j] *= alpha[j];

    // ---- P -> per-wave LDS (D-layout) -> A-fragments (swizzled) ----
#pragma unroll
    for (int n = 0; n < 4; ++n) {
      const int col = n * 16 + c16;
      const int cb = col >> 3, o = col & 7;
#pragma unroll
      for (int j = 0; j < 4; ++j) {
        const int row = g * 4 + j;
        Pw[row * 64 + ((cb ^ (row & 7)) << 3) + o] = f2bf(sc[n][j]);
      }
    }
    short8 aP[2];
#pragma unroll
    for (int kk = 0; kk < 2; ++kk) {
      const int row = c16;
      const int cch = (kk * 4 + g) ^ (row & 7);
      aP[kk] = *reinterpret_cast<const short8*>(&Pw[row * 64 + cch * 8]);
    }

    // ---- PV (V^T frags straight from L2) ----
#pragma unroll
    for (int dt = 0; dt < 8; ++dt) {
      const short* vrow = vtb + (size_t)(dt * 16 + c16) * 1024 + kv0 + g * 8;
#pragma unroll
      for (int kk = 0; kk < 2; ++kk) {
        short8 bV = *reinterpret_cast<const short8*>(vrow + kk * 32);
        accO[dt] = __builtin_amdgcn_mfma_f32_16x16x32_bf16(aP[kk], bV, accO[dt], 0, 0, 0);
      }
    }
  }

  // ---- epilogue: normalize and store bf16 [B,T,D] ----
#pragma unroll
  for (int j = 0; j < 4; ++j) {
    const float inv = 1.0f / l_r[j];
    const size_t rowoff = (size_t)(b * 1024 + q0w + g * 4 + j) * 1024 + h * 128;
#pragma unroll
    for (int dt = 0; dt < 8; ++dt)
      attnb[rowoff + dt * 16 + c16] = f2bf(accO[dt][j] * inv);
  }
}

extern "C" void kernel_launch(void* const* d_in, const int* in_sizes, int n_in,
                              void* d_out, int out_size, void* d_ws, size_t ws_size,
                              hipStream_t stream) {
  const float* x = (const float*)d_in[0];
  const float* Wqkv = (const float*)d_in[1];
  const float* Wout = (const float*)d_in[2];
  const float* hscale = (const float*)d_in[3];
  const float* hdirs = (const float*)d_in[4];
  float* out = (float*)d_out;

  char* ws = (char*)d_ws;
  short* xb = (short*)(ws);                                  // 8 MB (dead after gemm1)
  short* wqkvT = (short*)(ws + (size_t)8 * 1024 * 1024);     // 6 MB
  short* woutT = (short*)(ws + (size_t)14 * 1024 * 1024);    // 2 MB
  short* qkvb = (short*)(ws + (size_t)16 * 1024 * 1024);     // 24 MB
  short* vT = (short*)(ws + (size_t)40 * 1024 * 1024);       // 8 MB
  short* attnb = (short*)(ws + (size_t)48 * 1024 * 1024);    // 8 MB
  float* kproj = (float*)(ws);                               // 128 KB, reuses dead xb region

  cvt_kernel<<<2048, 256, 0, stream>>>(x, xb, (4 * 1024 * 1024) / 4);
  tcvt_kernel<<<dim3(96, 32), 256, 0, stream>>>(Wqkv, wqkvT, 1024, 3072);
  tcvt_kernel<<<dim3(32, 32), 256, 0, stream>>>(Wout, woutT, 1024, 1024);
  gemm_kernel<1><<<dim3(24, 32), 256, 0, stream>>>(xb, wqkvT, (void*)qkvb, 1024, 3072);
  kproj_kernel<<<128, 256, 0, stream>>>(qkvb, hdirs, kproj);
  vtrans_kernel<<<dim3(16, 16, 4), 256, 0, stream>>>(qkvb, vT);
  attn_kernel<<<512, 256, 0, stream>>>(qkvb, vT, hscale, hdirs, kproj, attnb);
  gemm_kernel<0><<<dim3(8, 32), 256, 0, stream>>>(attnb, woutT, out, 1024, 1024);
}

// Round 3
// 123.628 us; speedup vs baseline: 1.3732x; 1.3732x over previous
//
#include <hip/hip_runtime.h>
#include <stdint.h>

typedef __attribute__((ext_vector_type(8))) short short8;
typedef __attribute__((ext_vector_type(4))) short short4v;
typedef __attribute__((ext_vector_type(4))) float f32x4;

__device__ __forceinline__ short f2bf(float x) {
  union { float f; uint32_t u; } c; c.f = x;
  uint32_t r = (c.u + 0x7FFFu + ((c.u >> 16) & 1u)) >> 16;
  return (short)r;
}
__device__ __forceinline__ float b2f(short s) {
  union { uint32_t u; float f; } c; c.u = ((uint32_t)(uint16_t)s) << 16;
  return c.f;
}

// ---------------- fp32 -> bf16 convert (vectorized) ----------------
__global__ __launch_bounds__(256) void cvt_kernel(const float* __restrict__ in,
                                                  short* __restrict__ out, int n4) {
  int i = blockIdx.x * 256 + threadIdx.x;
  const int stride = gridDim.x * 256;
  for (; i < n4; i += stride) {
    float4 v = reinterpret_cast<const float4*>(in)[i];
    short4v o;
    o.x = f2bf(v.x); o.y = f2bf(v.y); o.z = f2bf(v.z); o.w = f2bf(v.w);
    reinterpret_cast<short4v*>(out)[i] = o;
  }
}

// ------------- fp32 [K][N] -> bf16 [N][K] transpose-convert -------------
__global__ __launch_bounds__(256) void tcvt_kernel(const float* __restrict__ in,
                                                   short* __restrict__ out, int K, int N) {
  __shared__ __align__(16) short tile[32][33];
  const int nb = blockIdx.x * 32, kb = blockIdx.y * 32;
  const int tx = threadIdx.x & 31, ty = threadIdx.x >> 5; // 32 x 8
#pragma unroll
  for (int i = 0; i < 32; i += 8)
    tile[ty + i][tx] = f2bf(in[(size_t)(kb + ty + i) * N + nb + tx]);
  __syncthreads();
#pragma unroll
  for (int i = 0; i < 32; i += 8)
    out[(size_t)(nb + ty + i) * K + kb + tx] = tile[tx][ty + i];
}

// ------------- bf16 V-region transpose: qkv[b][kv][2048+c] -> vT[b][c][kv] -------------
__global__ __launch_bounds__(256) void vtrans_kernel(const short* __restrict__ qkvb,
                                                     short* __restrict__ vT) {
  __shared__ __align__(16) short tile[64][65];
  const int b = blockIdx.z;
  const int kv0 = blockIdx.x * 64, c0 = blockIdx.y * 64;
  const int tx = threadIdx.x & 15, ty = threadIdx.x >> 4; // 16 x 16
  const short* src = qkvb + (size_t)(b * 1024) * 3072 + 2048;
#pragma unroll
  for (int i = 0; i < 64; i += 16) {
    int r = ty + i;
#pragma unroll
    for (int j = 0; j < 4; ++j)
      tile[r][tx * 4 + j] = src[(size_t)(kv0 + r) * 3072 + c0 + tx * 4 + j];
  }
  __syncthreads();
  short* dst = vT + (size_t)b * 1024 * 1024;
#pragma unroll
  for (int i = 0; i < 64; i += 16) {
    int cc = ty + i;
#pragma unroll
    for (int j = 0; j < 4; ++j)
      dst[(size_t)(c0 + cc) * 1024 + kv0 + tx * 4 + j] = tile[tx * 4 + j][cc];
  }
}

// ------------- k-projection precompute: kproj[bh][t] = dot(K[b,t,h,0:3], dir_h) -------------
__global__ __launch_bounds__(256) void kproj_kernel(const short* __restrict__ qkvb,
                                                    const float* __restrict__ hdirs,
                                                    float* __restrict__ kproj) {
  const int i = blockIdx.x * 256 + threadIdx.x; // over 32*1024
  const int bh = i >> 10, tt = i & 1023;
  const int b = bh >> 3, h = bh & 7;
  const float d0 = hdirs[h * 3], d1 = hdirs[h * 3 + 1], d2 = hdirs[h * 3 + 2];
  const short* kr = qkvb + (size_t)(b * 1024 + tt) * 3072 + 1024 + h * 128;
  kproj[i] = b2f(kr[0]) * d0 + b2f(kr[1]) * d1 + b2f(kr[2]) * d2;
}

// ---------------- bf16 MFMA GEMM: C[M][N] = A[M][K] * Bt[N][K]^T ----------------
template <int OUT_BF16>
__global__ __launch_bounds__(256) void gemm_kernel(const short* __restrict__ A,
                                                   const short* __restrict__ Bt,
                                                   void* __restrict__ Cout,
                                                   int K, int ldc) {
  __shared__ __align__(16) short Al[2][128 * 32];
  __shared__ __align__(16) short Bl[2][128 * 32];
  const int t = threadIdx.x;
  const int lane = t & 63, w = t >> 6;
  const int wr = w >> 1, wc = w & 1;
  const int g = lane >> 4, c16 = lane & 15;
  const int row0 = blockIdx.y * 128, col0 = blockIdx.x * 128;

  f32x4 acc[4][4];
#pragma unroll
  for (int m = 0; m < 4; ++m)
#pragma unroll
    for (int n = 0; n < 4; ++n) {
      f32x4 z = {0.0f, 0.0f, 0.0f, 0.0f};
      acc[m][n] = z;
    }

  auto stage = [&](int buf, int kt) {
    const int k0 = kt * 32;
#pragma unroll
    for (int i = 0; i < 2; ++i) {
      const int qb = i * 256 + (t & 192); // wave-uniform chunk base
      const int q = qb + lane;
      const int r = q >> 2;
      const int c = (q & 3) ^ ((r >> 1) & 3);
      const short* ga = A + (size_t)(row0 + r) * K + k0 + c * 8;
      const short* gb = Bt + (size_t)(col0 + r) * K + k0 + c * 8;
      __builtin_amdgcn_global_load_lds((const __attribute__((address_space(1))) void*)ga,
                                       (__attribute__((address_space(3))) void*)&Al[buf][qb * 8],
                                       16, 0, 0);
      __builtin_amdgcn_global_load_lds((const __attribute__((address_space(1))) void*)gb,
                                       (__attribute__((address_space(3))) void*)&Bl[buf][qb * 8],
                                       16, 0, 0);
    }
  };

  stage(0, 0);
  __syncthreads();
  const int NK = K >> 5;
  int cur = 0;
  const int rA0 = wr * 64 + c16;
  const int rB0 = wc * 64 + c16;
  for (int kt = 0; kt < NK; ++kt) {
    if (kt + 1 < NK) stage(cur ^ 1, kt + 1);
    short8 aF[4], bF[4];
#pragma unroll
    for (int m = 0; m < 4; ++m) {
      const int r = rA0 + m * 16;
      const int c = g ^ ((r >> 1) & 3);
      aF[m] = *reinterpret_cast<const short8*>(&Al[cur][r * 32 + c * 8]);
    }
#pragma unroll
    for (int n = 0; n < 4; ++n) {
      const int r = rB0 + n * 16;
      const int c = g ^ ((r >> 1) & 3);
      bF[n] = *reinterpret_cast<const short8*>(&Bl[cur][r * 32 + c * 8]);
    }
#pragma unroll
    for (int m = 0; m < 4; ++m)
#pragma unroll
      for (int n = 0; n < 4; ++n)
        acc[m][n] = __builtin_amdgcn_mfma_f32_16x16x32_bf16(aF[m], bF[n], acc[m][n], 0, 0, 0);
    __syncthreads();
    cur ^= 1;
  }

  const int er = row0 + wr * 64 + g * 4;
  const int ec = col0 + wc * 64 + c16;
#pragma unroll
  for (int m = 0; m < 4; ++m)
#pragma unroll
    for (int n = 0; n < 4; ++n)
#pragma unroll
      for (int j = 0; j < 4; ++j) {
        const size_t off = (size_t)(er + m * 16 + j) * ldc + ec + n * 16;
        if (OUT_BF16)
          ((short*)Cout)[off] = f2bf(acc[m][n][j]);
        else
          ((float*)Cout)[off] = acc[m][n][j];
      }
}

// ---------------- fused causal attention with trigram geo bias ----------------
// 256 blocks; block = (pair p, bh). Processes q-tiles p and 15-p (uniform 17
// tile-computes/block). K/V LDS double-buffered, staged via global_load_lds
// issued BEFORE compute (2-phase pipeline), one barrier per kv-tile.
__global__ __launch_bounds__(256) void attn_kernel(const short* __restrict__ qkvb,
                                                   const short* __restrict__ vT,
                                                   const float* __restrict__ head_scales,
                                                   const float* __restrict__ hdirs,
                                                   const float* __restrict__ kproj,
                                                   short* __restrict__ attnb) {
  __shared__ __align__(16) short Kl[2][64 * 128];
  __shared__ __align__(16) short Vl[2][128 * 64];
  __shared__ __align__(16) short P_lds[4][16 * 64];

  const int bid = blockIdx.x;       // 0..255 ; bid = p*32 + bh keeps all pairs
  const int bh = bid & 31;          // of a bh on one XCD (stride 32 % 8 == 0)
  const int p = bid >> 5;
  const int qtA = p, qtB = 15 - p;  // qtA < qtB always (p<=7)
  const int b = bh >> 3, h = bh & 7;
  const int t = threadIdx.x, lane = t & 63, w = t >> 6;
  const int g = lane >> 4, c16 = lane & 15;
  const int q0A = qtA * 64 + w * 16, q0B = qtB * 64 + w * 16;

  const short* qbase = qkvb + (size_t)(b * 1024) * 3072 + h * 128;
  const short* kbase = qbase + 1024;
  const short* vtb = vT + (size_t)bh * 128 * 1024;
  const float* kp = kproj + bh * 1024;

  const float hs = head_scales[h];
  const float d0 = hdirs[h * 3], d1 = hdirs[h * 3 + 1], d2 = hdirs[h * 3 + 2];
  const float scale = 0.08838834764831845f; // 1/sqrt(128)

  // Q fragments + geo q-projections for both tiles
  short8 aQA[4], aQB[4];
  float hqpA[4], hqpB[4];
  {
    const short* qrA = qbase + (size_t)(q0A + c16) * 3072 + g * 8;
    const short* qrB = qbase + (size_t)(q0B + c16) * 3072 + g * 8;
#pragma unroll
    for (int kk = 0; kk < 4; ++kk) {
      aQA[kk] = *reinterpret_cast<const short8*>(qrA + kk * 32);
      aQB[kk] = *reinterpret_cast<const short8*>(qrB + kk * 32);
    }
#pragma unroll
    for (int j = 0; j < 4; ++j) {
      const short* qa = qbase + (size_t)(q0A + g * 4 + j) * 3072;
      const short* qb = qbase + (size_t)(q0B + g * 4 + j) * 3072;
      hqpA[j] = hs * (b2f(qa[0]) * d0 + b2f(qa[1]) * d1 + b2f(qa[2]) * d2);
      hqpB[j] = hs * (b2f(qb[0]) * d0 + b2f(qb[1]) * d1 + b2f(qb[2]) * d2);
    }
  }

  float mA[4], lA[4], mB[4], lB[4];
  f32x4 accA[8], accB[8];
#pragma unroll
  for (int j = 0; j < 4; ++j) { mA[j] = -1e30f; lA[j] = 0.0f; mB[j] = -1e30f; lB[j] = 0.0f; }
#pragma unroll
  for (int d = 0; d < 8; ++d) {
    f32x4 z = {0.0f, 0.0f, 0.0f, 0.0f};
    accA[d] = z; accB[d] = z;
  }

  short* Pw = P_lds[w];

  auto stageKV = [&](int buf, int kvt) {
    const int kv0 = kvt * 64;
#pragma unroll
    for (int i = 0; i < 4; ++i) {
      const int s = w * 4 + i;
      {
        const int r = s * 4 + g;            // kv row
        const int c = c16 ^ (r & 7);        // global 16B chunk (16/row)
        const short* ga = kbase + (size_t)(kv0 + r) * 3072 + c * 8;
        __builtin_amdgcn_global_load_lds((const __attribute__((address_space(1))) void*)ga,
                                         (__attribute__((address_space(3))) void*)&Kl[buf][s * 512],
                                         16, 0, 0);
      }
      {
        const int r = s * 8 + (lane >> 3);  // d row
        const int c = (lane & 7) ^ (r & 7); // global 16B chunk (8/row)
        const short* ga = vtb + (size_t)r * 1024 + kv0 + c * 8;
        __builtin_amdgcn_global_load_lds((const __attribute__((address_space(1))) void*)ga,
                                         (__attribute__((address_space(3))) void*)&Vl[buf][s * 512],
                                         16, 0, 0);
      }
    }
  };

  auto computeTile = [&](int kvt, int q0w, const short8* aQ, const float* hqp,
                         float* m_r, float* l_r, f32x4* accO,
                         const short* Kc, const short* Vc) {
    const int kv0 = kvt * 64;
    float sc[4][4];
#pragma unroll
    for (int n = 0; n < 4; ++n) {
      f32x4 s4 = {0.0f, 0.0f, 0.0f, 0.0f};
      const int r = n * 16 + c16; // kv index within tile
#pragma unroll
      for (int kk = 0; kk < 4; ++kk) {
        const int cch = (kk * 4 + g) ^ (r & 7);
        short8 bK = *reinterpret_cast<const short8*>(&Kc[r * 128 + cch * 8]);
        s4 = __builtin_amdgcn_mfma_f32_16x16x32_bf16(aQ[kk], bK, s4, 0, 0, 0);
      }
      const float kpv = kp[kv0 + r];
      const int ka = kv0 + r;
#pragma unroll
      for (int j = 0; j < 4; ++j) {
        const int qa = q0w + g * 4 + j;
        const float v = s4[j] * scale + hqp[j] * kpv;
        sc[n][j] = (ka <= qa) ? v : -1e30f;
      }
    }
    // online softmax (row reduce across 16 lanes of the group)
    float mx[4];
#pragma unroll
    for (int j = 0; j < 4; ++j) {
      float v = fmaxf(fmaxf(sc[0][j], sc[1][j]), fmaxf(sc[2][j], sc[3][j]));
#pragma unroll
      for (int off = 8; off > 0; off >>= 1) v = fmaxf(v, __shfl_xor(v, off, 16));
      mx[j] = v;
    }
    float alpha[4], psum[4];
#pragma unroll
    for (int j = 0; j < 4; ++j) {
      const float mn = fmaxf(m_r[j], mx[j]);
      alpha[j] = __expf(m_r[j] - mn);
      m_r[j] = mn;
      float ps = 0.0f;
#pragma unroll
      for (int n = 0; n < 4; ++n) {
        const float pv = __expf(sc[n][j] - mn);
        sc[n][j] = pv;
        ps += pv;
      }
      psum[j] = ps;
    }
#pragma unroll
    for (int j = 0; j < 4; ++j) {
      float ps = psum[j];
#pragma unroll
      for (int off = 8; off > 0; off >>= 1) ps += __shfl_xor(ps, off, 16);
      l_r[j] = l_r[j] * alpha[j] + ps;
    }
#pragma unroll
    for (int d = 0; d < 8; ++d)
#pragma unroll
      for (int j = 0; j < 4; ++j) accO[d][j] *= alpha[j];

    // P -> per-wave LDS (swizzled) -> A-fragments
#pragma unroll
    for (int n = 0; n < 4; ++n) {
      const int col = n * 16 + c16;
      const int cb = col >> 3, o = col & 7;
#pragma unroll
      for (int j = 0; j < 4; ++j) {
        const int row = g * 4 + j;
        Pw[row * 64 + ((cb ^ (row & 7)) << 3) + o] = f2bf(sc[n][j]);
      }
    }
    short8 aP[2];
#pragma unroll
    for (int kk = 0; kk < 2; ++kk) {
      const int row = c16;
      const int cch = (kk * 4 + g) ^ (row & 7);
      aP[kk] = *reinterpret_cast<const short8*>(&Pw[row * 64 + cch * 8]);
    }
    // PV
#pragma unroll
    for (int dt = 0; dt < 8; ++dt) {
      const int r = dt * 16 + c16; // d row in Vl
#pragma unroll
      for (int kk = 0; kk < 2; ++kk) {
        const int cch = (kk * 4 + g) ^ (r & 7);
        short8 bV = *reinterpret_cast<const short8*>(&Vc[r * 64 + cch * 8]);
        accO[dt] = __builtin_amdgcn_mfma_f32_16x16x32_bf16(aP[kk], bV, accO[dt], 0, 0, 0);
      }
    }
  };

  const int nkv = qtB + 1;
  stageKV(0, 0);
  __syncthreads();
  int cur = 0;
  for (int kvt = 0; kvt < nkv; ++kvt) {
    if (kvt + 1 < nkv) stageKV(cur ^ 1, kvt + 1); // prefetch overlaps compute
    computeTile(kvt, q0B, aQB, hqpB, mB, lB, accB, Kl[cur], Vl[cur]);
    if (kvt <= qtA)
      computeTile(kvt, q0A, aQA, hqpA, mA, lA, accA, Kl[cur], Vl[cur]);
    __syncthreads(); // drains vmcnt (next buffer ready) + all waves done reading cur
    cur ^= 1;
  }

  // epilogue: normalize and store bf16 [B,T,D]
#pragma unroll
  for (int j = 0; j < 4; ++j) {
    const float invA = 1.0f / lA[j];
    const float invB = 1.0f / lB[j];
    const size_t rowA = (size_t)(b * 1024 + q0A + g * 4 + j) * 1024 + h * 128;
    const size_t rowB = (size_t)(b * 1024 + q0B + g * 4 + j) * 1024 + h * 128;
#pragma unroll
    for (int dt = 0; dt < 8; ++dt) {
      attnb[rowA + dt * 16 + c16] = f2bf(accA[dt][j] * invA);
      attnb[rowB + dt * 16 + c16] = f2bf(accB[dt][j] * invB);
    }
  }
}

extern "C" void kernel_launch(void* const* d_in, const int* in_sizes, int n_in,
                              void* d_out, int out_size, void* d_ws, size_t ws_size,
                              hipStream_t stream) {
  const float* x = (const float*)d_in[0];
  const float* Wqkv = (const float*)d_in[1];
  const float* Wout = (const float*)d_in[2];
  const float* hscale = (const float*)d_in[3];
  const float* hdirs = (const float*)d_in[4];
  float* out = (float*)d_out;

  char* ws = (char*)d_ws;
  short* xb = (short*)(ws);                                  // 8 MB (dead after gemm1)
  short* wqkvT = (short*)(ws + (size_t)8 * 1024 * 1024);     // 6 MB
  short* woutT = (short*)(ws + (size_t)14 * 1024 * 1024);    // 2 MB
  short* qkvb = (short*)(ws + (size_t)16 * 1024 * 1024);     // 24 MB
  short* vT = (short*)(ws + (size_t)40 * 1024 * 1024);       // 8 MB
  short* attnb = (short*)(ws + (size_t)48 * 1024 * 1024);    // 8 MB
  float* kproj = (float*)(ws);                               // 128 KB, reuses dead xb region

  cvt_kernel<<<2048, 256, 0, stream>>>(x, xb, (4 * 1024 * 1024) / 4);
  tcvt_kernel<<<dim3(96, 32), 256, 0, stream>>>(Wqkv, wqkvT, 1024, 3072);
  tcvt_kernel<<<dim3(32, 32), 256, 0, stream>>>(Wout, woutT, 1024, 1024);
  gemm_kernel<1><<<dim3(24, 32), 256, 0, stream>>>(xb, wqkvT, (void*)qkvb, 1024, 3072);
  kproj_kernel<<<128, 256, 0, stream>>>(qkvb, hdirs, kproj);
  vtrans_kernel<<<dim3(16, 16, 4), 256, 0, stream>>>(qkvb, vT);
  attn_kernel<<<256, 256, 0, stream>>>(qkvb, vT, hscale, hdirs, kproj, attnb);
  gemm_kernel<0><<<dim3(8, 32), 256, 0, stream>>>(attnb, woutT, out, 1024, 1024);
}

// Round 4
// 118.636 us; speedup vs baseline: 1.4310x; 1.0421x over previous
//
#include <hip/hip_runtime.h>
#include <stdint.h>

typedef __attribute__((ext_vector_type(8))) short short8;
typedef __attribute__((ext_vector_type(4))) short short4v;
typedef __attribute__((ext_vector_type(4))) float f32x4;

__device__ __forceinline__ short f2bf(float x) {
  union { float f; uint32_t u; } c; c.f = x;
  uint32_t r = (c.u + 0x7FFFu + ((c.u >> 16) & 1u)) >> 16;
  return (short)r;
}
__device__ __forceinline__ float b2f(short s) {
  union { uint32_t u; float f; } c; c.u = ((uint32_t)(uint16_t)s) << 16;
  return c.f;
}

// ---------------- fp32 -> bf16 convert (vectorized) ----------------
__global__ __launch_bounds__(256) void cvt_kernel(const float* __restrict__ in,
                                                  short* __restrict__ out, int n4) {
  int i = blockIdx.x * 256 + threadIdx.x;
  const int stride = gridDim.x * 256;
  for (; i < n4; i += stride) {
    float4 v = reinterpret_cast<const float4*>(in)[i];
    short4v o;
    o.x = f2bf(v.x); o.y = f2bf(v.y); o.z = f2bf(v.z); o.w = f2bf(v.w);
    reinterpret_cast<short4v*>(out)[i] = o;
  }
}

// ------------- fp32 [K][N] -> bf16 [N][K] transpose-convert -------------
__global__ __launch_bounds__(256) void tcvt_kernel(const float* __restrict__ in,
                                                   short* __restrict__ out, int K, int N) {
  __shared__ __align__(16) short tile[32][33];
  const int nb = blockIdx.x * 32, kb = blockIdx.y * 32;
  const int tx = threadIdx.x & 31, ty = threadIdx.x >> 5; // 32 x 8
#pragma unroll
  for (int i = 0; i < 32; i += 8)
    tile[ty + i][tx] = f2bf(in[(size_t)(kb + ty + i) * N + nb + tx]);
  __syncthreads();
#pragma unroll
  for (int i = 0; i < 32; i += 8)
    out[(size_t)(nb + ty + i) * K + kb + tx] = tile[tx][ty + i];
}

// ------------- bf16 V-region transpose: qkv[b][kv][2048+c] -> vT[b][c][kv] -------------
__global__ __launch_bounds__(256) void vtrans_kernel(const short* __restrict__ qkvb,
                                                     short* __restrict__ vT) {
  __shared__ __align__(16) short tile[64][65];
  const int b = blockIdx.z;
  const int kv0 = blockIdx.x * 64, c0 = blockIdx.y * 64;
  const int tx = threadIdx.x & 15, ty = threadIdx.x >> 4; // 16 x 16
  const short* src = qkvb + (size_t)(b * 1024) * 3072 + 2048;
#pragma unroll
  for (int i = 0; i < 64; i += 16) {
    int r = ty + i;
#pragma unroll
    for (int j = 0; j < 4; ++j)
      tile[r][tx * 4 + j] = src[(size_t)(kv0 + r) * 3072 + c0 + tx * 4 + j];
  }
  __syncthreads();
  short* dst = vT + (size_t)b * 1024 * 1024;
#pragma unroll
  for (int i = 0; i < 64; i += 16) {
    int cc = ty + i;
#pragma unroll
    for (int j = 0; j < 4; ++j)
      dst[(size_t)(c0 + cc) * 1024 + kv0 + tx * 4 + j] = tile[tx * 4 + j][cc];
  }
}

// ------------- k-projection precompute: kproj[bh][t] = dot(K[b,t,h,0:3], dir_h) -------------
__global__ __launch_bounds__(256) void kproj_kernel(const short* __restrict__ qkvb,
                                                    const float* __restrict__ hdirs,
                                                    float* __restrict__ kproj) {
  const int i = blockIdx.x * 256 + threadIdx.x; // over 32*1024
  const int bh = i >> 10, tt = i & 1023;
  const int b = bh >> 3, h = bh & 7;
  const float d0 = hdirs[h * 3], d1 = hdirs[h * 3 + 1], d2 = hdirs[h * 3 + 2];
  const short* kr = qkvb + (size_t)(b * 1024 + tt) * 3072 + 1024 + h * 128;
  kproj[i] = b2f(kr[0]) * d0 + b2f(kr[1]) * d1 + b2f(kr[2]) * d2;
}

// ---------------- bf16 MFMA GEMM: C[M][N] = A[M][K] * Bt[N][K]^T ----------------
template <int OUT_BF16>
__global__ __launch_bounds__(256) void gemm_kernel(const short* __restrict__ A,
                                                   const short* __restrict__ Bt,
                                                   void* __restrict__ Cout,
                                                   int K, int ldc) {
  __shared__ __align__(16) short Al[2][128 * 32];
  __shared__ __align__(16) short Bl[2][128 * 32];
  const int t = threadIdx.x;
  const int lane = t & 63, w = t >> 6;
  const int wr = w >> 1, wc = w & 1;
  const int g = lane >> 4, c16 = lane & 15;
  const int row0 = blockIdx.y * 128, col0 = blockIdx.x * 128;

  f32x4 acc[4][4];
#pragma unroll
  for (int m = 0; m < 4; ++m)
#pragma unroll
    for (int n = 0; n < 4; ++n) {
      f32x4 z = {0.0f, 0.0f, 0.0f, 0.0f};
      acc[m][n] = z;
    }

  auto stage = [&](int buf, int kt) {
    const int k0 = kt * 32;
#pragma unroll
    for (int i = 0; i < 2; ++i) {
      const int qb = i * 256 + (t & 192); // wave-uniform chunk base
      const int q = qb + lane;
      const int r = q >> 2;
      const int c = (q & 3) ^ ((r >> 1) & 3);
      const short* ga = A + (size_t)(row0 + r) * K + k0 + c * 8;
      const short* gb = Bt + (size_t)(col0 + r) * K + k0 + c * 8;
      __builtin_amdgcn_global_load_lds((const __attribute__((address_space(1))) void*)ga,
                                       (__attribute__((address_space(3))) void*)&Al[buf][qb * 8],
                                       16, 0, 0);
      __builtin_amdgcn_global_load_lds((const __attribute__((address_space(1))) void*)gb,
                                       (__attribute__((address_space(3))) void*)&Bl[buf][qb * 8],
                                       16, 0, 0);
    }
  };

  stage(0, 0);
  __syncthreads();
  const int NK = K >> 5;
  int cur = 0;
  const int rA0 = wr * 64 + c16;
  const int rB0 = wc * 64 + c16;
  for (int kt = 0; kt < NK; ++kt) {
    if (kt + 1 < NK) stage(cur ^ 1, kt + 1);
    short8 aF[4], bF[4];
#pragma unroll
    for (int m = 0; m < 4; ++m) {
      const int r = rA0 + m * 16;
      const int c = g ^ ((r >> 1) & 3);
      aF[m] = *reinterpret_cast<const short8*>(&Al[cur][r * 32 + c * 8]);
    }
#pragma unroll
    for (int n = 0; n < 4; ++n) {
      const int r = rB0 + n * 16;
      const int c = g ^ ((r >> 1) & 3);
      bF[n] = *reinterpret_cast<const short8*>(&Bl[cur][r * 32 + c * 8]);
    }
#pragma unroll
    for (int m = 0; m < 4; ++m)
#pragma unroll
      for (int n = 0; n < 4; ++n)
        acc[m][n] = __builtin_amdgcn_mfma_f32_16x16x32_bf16(aF[m], bF[n], acc[m][n], 0, 0, 0);
    __syncthreads();
    cur ^= 1;
  }

  const int er = row0 + wr * 64 + g * 4;
  const int ec = col0 + wc * 64 + c16;
#pragma unroll
  for (int m = 0; m < 4; ++m)
#pragma unroll
    for (int n = 0; n < 4; ++n)
#pragma unroll
      for (int j = 0; j < 4; ++j) {
        const size_t off = (size_t)(er + m * 16 + j) * ldc + ec + n * 16;
        if (OUT_BF16)
          ((short*)Cout)[off] = f2bf(acc[m][n][j]);
        else
          ((float*)Cout)[off] = acc[m][n][j];
      }
}

// ---------------- fused causal attention with trigram geo bias ----------------
// 512 blocks, one q-tile each, qt DESCENDING in blockIdx (LPT backfill), bh
// clustered 4-per-XCD. 72KB LDS -> 2 blocks/CU (2 waves/SIMD). K/V double-
// buffered via global_load_lds prefetch. Row-sum via ones-MFMA (no shfl);
// defer-max (T13, THR=8) skips most rescales.
__global__ __launch_bounds__(256) void attn_kernel(const short* __restrict__ qkvb,
                                                   const short* __restrict__ vT,
                                                   const float* __restrict__ head_scales,
                                                   const float* __restrict__ hdirs,
                                                   const float* __restrict__ kproj,
                                                   short* __restrict__ attnb) {
  __shared__ __align__(16) short Kl[2][64 * 128];
  __shared__ __align__(16) short Vl[2][128 * 64];
  __shared__ __align__(16) short P_lds[4][16 * 64];

  const int bid = blockIdx.x;                       // 0..511
  const int bh = (bid & 7) * 4 + ((bid >> 3) & 3);  // 4 bh per XCD
  const int qt = 15 - (bid >> 5);                   // big tiles dispatched first
  const int b = bh >> 3, h = bh & 7;
  const int t = threadIdx.x, lane = t & 63, w = t >> 6;
  const int g = lane >> 4, c16 = lane & 15;
  const int q0w = qt * 64 + w * 16;

  const short* qbase = qkvb + (size_t)(b * 1024) * 3072 + h * 128;
  const short* kbase = qbase + 1024;
  const short* vtb = vT + (size_t)bh * 128 * 1024;
  const float* kp = kproj + bh * 1024;

  const float hs = head_scales[h];
  const float d0 = hdirs[h * 3], d1 = hdirs[h * 3 + 1], d2 = hdirs[h * 3 + 2];
  const float scale = 0.08838834764831845f; // 1/sqrt(128)

  short8 aQ[4];
  float hqp[4];
  {
    const short* qr = qbase + (size_t)(q0w + c16) * 3072 + g * 8;
#pragma unroll
    for (int kk = 0; kk < 4; ++kk) aQ[kk] = *reinterpret_cast<const short8*>(qr + kk * 32);
#pragma unroll
    for (int j = 0; j < 4; ++j) {
      const short* qa = qbase + (size_t)(q0w + g * 4 + j) * 3072;
      hqp[j] = hs * (b2f(qa[0]) * d0 + b2f(qa[1]) * d1 + b2f(qa[2]) * d2);
    }
  }

  float m_r[4], l_r[4];
  f32x4 accO[8];
#pragma unroll
  for (int j = 0; j < 4; ++j) { m_r[j] = -1e30f; l_r[j] = 0.0f; }
#pragma unroll
  for (int d = 0; d < 8; ++d) {
    f32x4 z = {0.0f, 0.0f, 0.0f, 0.0f};
    accO[d] = z;
  }

  short* Pw = P_lds[w];
  const short8 onesb = {(short)0x3F80, (short)0x3F80, (short)0x3F80, (short)0x3F80,
                        (short)0x3F80, (short)0x3F80, (short)0x3F80, (short)0x3F80};

  auto stageKV = [&](int buf, int kvt) {
    const int kv0 = kvt * 64;
#pragma unroll
    for (int i = 0; i < 4; ++i) {
      const int s = w * 4 + i;
      {
        const int r = s * 4 + g;            // kv row
        const int c = c16 ^ (r & 7);        // global 16B chunk (16/row)
        const short* ga = kbase + (size_t)(kv0 + r) * 3072 + c * 8;
        __builtin_amdgcn_global_load_lds((const __attribute__((address_space(1))) void*)ga,
                                         (__attribute__((address_space(3))) void*)&Kl[buf][s * 512],
                                         16, 0, 0);
      }
      {
        const int r = s * 8 + (lane >> 3);  // d row
        const int c = (lane & 7) ^ (r & 7); // global 16B chunk (8/row)
        const short* ga = vtb + (size_t)r * 1024 + kv0 + c * 8;
        __builtin_amdgcn_global_load_lds((const __attribute__((address_space(1))) void*)ga,
                                         (__attribute__((address_space(3))) void*)&Vl[buf][s * 512],
                                         16, 0, 0);
      }
    }
  };

  const int nkv = qt + 1;
  stageKV(0, 0);
  __syncthreads();
  int cur = 0;
  for (int kvt = 0; kvt < nkv; ++kvt) {
    const int kv0 = kvt * 64;
    if (kvt + 1 < nkv) stageKV(cur ^ 1, kvt + 1); // prefetch overlaps compute
    const short* Kc = Kl[cur];
    const short* Vc = Vl[cur];

    // ---- QK^T + scale + geo bias + causal mask ----
    float sc[4][4];
#pragma unroll
    for (int n = 0; n < 4; ++n) {
      f32x4 s4 = {0.0f, 0.0f, 0.0f, 0.0f};
      const int r = n * 16 + c16; // kv index within tile
#pragma unroll
      for (int kk = 0; kk < 4; ++kk) {
        const int cch = (kk * 4 + g) ^ (r & 7);
        short8 bK = *reinterpret_cast<const short8*>(&Kc[r * 128 + cch * 8]);
        s4 = __builtin_amdgcn_mfma_f32_16x16x32_bf16(aQ[kk], bK, s4, 0, 0, 0);
      }
      const float kpv = kp[kv0 + r];
      const int ka = kv0 + r;
#pragma unroll
      for (int j = 0; j < 4; ++j) {
        const int qa = q0w + g * 4 + j;
        const float v = s4[j] * scale + hqp[j] * kpv;
        sc[n][j] = (ka <= qa) ? v : -1e30f;
      }
    }

    // ---- row max (16-lane butterfly) + defer-max rescale decision ----
    float mx[4];
#pragma unroll
    for (int j = 0; j < 4; ++j) {
      float v = fmaxf(fmaxf(sc[0][j], sc[1][j]), fmaxf(sc[2][j], sc[3][j]));
#pragma unroll
      for (int off = 8; off > 0; off >>= 1) v = fmaxf(v, __shfl_xor(v, off, 16));
      mx[j] = v;
    }
    const float dm = fmaxf(fmaxf(mx[0] - m_r[0], mx[1] - m_r[1]),
                           fmaxf(mx[2] - m_r[2], mx[3] - m_r[3]));
    if (__any(dm > 8.0f)) {
#pragma unroll
      for (int j = 0; j < 4; ++j) {
        const float mn = fmaxf(m_r[j], mx[j]);
        const float alpha = __expf(m_r[j] - mn);
        m_r[j] = mn;
        l_r[j] *= alpha;
#pragma unroll
        for (int d = 0; d < 8; ++d) accO[d][j] *= alpha;
      }
    }
#pragma unroll
    for (int n = 0; n < 4; ++n)
#pragma unroll
      for (int j = 0; j < 4; ++j) sc[n][j] = __expf(sc[n][j] - m_r[j]);

    // ---- P -> per-wave LDS (swizzled) -> A-fragments ----
#pragma unroll
    for (int n = 0; n < 4; ++n) {
      const int col = n * 16 + c16;
      const int cb = col >> 3, o = col & 7;
#pragma unroll
      for (int j = 0; j < 4; ++j) {
        const int row = g * 4 + j;
        Pw[row * 64 + ((cb ^ (row & 7)) << 3) + o] = f2bf(sc[n][j]);
      }
    }
    short8 aP[2];
#pragma unroll
    for (int kk = 0; kk < 2; ++kk) {
      const int row = c16;
      const int cch = (kk * 4 + g) ^ (row & 7);
      aP[kk] = *reinterpret_cast<const short8*>(&Pw[row * 64 + cch * 8]);
    }

    // ---- row-sum via ones-MFMA (replaces 16-shfl butterfly) ----
    f32x4 accS = {0.0f, 0.0f, 0.0f, 0.0f};
    accS = __builtin_amdgcn_mfma_f32_16x16x32_bf16(aP[0], onesb, accS, 0, 0, 0);
    accS = __builtin_amdgcn_mfma_f32_16x16x32_bf16(aP[1], onesb, accS, 0, 0, 0);
#pragma unroll
    for (int j = 0; j < 4; ++j) l_r[j] += accS[j];

    // ---- PV ----
#pragma unroll
    for (int dt = 0; dt < 8; ++dt) {
      const int r = dt * 16 + c16; // d row in Vl
#pragma unroll
      for (int kk = 0; kk < 2; ++kk) {
        const int cch = (kk * 4 + g) ^ (r & 7);
        short8 bV = *reinterpret_cast<const short8*>(&Vc[r * 64 + cch * 8]);
        accO[dt] = __builtin_amdgcn_mfma_f32_16x16x32_bf16(aP[kk], bV, accO[dt], 0, 0, 0);
      }
    }
    __syncthreads(); // next buffer staged + all waves done reading cur
    cur ^= 1;
  }

  // ---- epilogue: normalize and store bf16 [B,T,D] ----
#pragma unroll
  for (int j = 0; j < 4; ++j) {
    const float inv = 1.0f / l_r[j];
    const size_t rowoff = (size_t)(b * 1024 + q0w + g * 4 + j) * 1024 + h * 128;
#pragma unroll
    for (int dt = 0; dt < 8; ++dt)
      attnb[rowoff + dt * 16 + c16] = f2bf(accO[dt][j] * inv);
  }
}

extern "C" void kernel_launch(void* const* d_in, const int* in_sizes, int n_in,
                              void* d_out, int out_size, void* d_ws, size_t ws_size,
                              hipStream_t stream) {
  const float* x = (const float*)d_in[0];
  const float* Wqkv = (const float*)d_in[1];
  const float* Wout = (const float*)d_in[2];
  const float* hscale = (const float*)d_in[3];
  const float* hdirs = (const float*)d_in[4];
  float* out = (float*)d_out;

  char* ws = (char*)d_ws;
  short* xb = (short*)(ws);                                  // 8 MB (dead after gemm1)
  short* wqkvT = (short*)(ws + (size_t)8 * 1024 * 1024);     // 6 MB
  short* woutT = (short*)(ws + (size_t)14 * 1024 * 1024);    // 2 MB
  short* qkvb = (short*)(ws + (size_t)16 * 1024 * 1024);     // 24 MB
  short* vT = (short*)(ws + (size_t)40 * 1024 * 1024);       // 8 MB
  short* attnb = (short*)(ws + (size_t)48 * 1024 * 1024);    // 8 MB
  float* kproj = (float*)(ws);                               // 128 KB, reuses dead xb region

  cvt_kernel<<<2048, 256, 0, stream>>>(x, xb, (4 * 1024 * 1024) / 4);
  tcvt_kernel<<<dim3(96, 32), 256, 0, stream>>>(Wqkv, wqkvT, 1024, 3072);
  tcvt_kernel<<<dim3(32, 32), 256, 0, stream>>>(Wout, woutT, 1024, 1024);
  gemm_kernel<1><<<dim3(24, 32), 256, 0, stream>>>(xb, wqkvT, (void*)qkvb, 1024, 3072);
  kproj_kernel<<<128, 256, 0, stream>>>(qkvb, hdirs, kproj);
  vtrans_kernel<<<dim3(16, 16, 4), 256, 0, stream>>>(qkvb, vT);
  attn_kernel<<<512, 256, 0, stream>>>(qkvb, vT, hscale, hdirs, kproj, attnb);
  gemm_kernel<0><<<dim3(8, 32), 256, 0, stream>>>(attnb, woutT, out, 1024, 1024);
}